// Round 5
// baseline (356.548 us; speedup 1.0000x reference)
//
#include <hip/hip_runtime.h>
#include <cstdint>
#include <cstddef>

#define N_DIM 4096
#define M_DIM 4096
#define D_DIM 4096

typedef unsigned short u16;
typedef u16   u16x8 __attribute__((ext_vector_type(8)));
typedef short s16x8 __attribute__((ext_vector_type(8)));   // 8 bf16 (4 VGPRs)
typedef float f32x4 __attribute__((ext_vector_type(4)));   // MFMA accumulator

// ---------- fp32 -> bf16 (RTNE) ----------
__device__ __forceinline__ u16 f2bf(float f) {
    union { float f; uint32_t u; } v; v.f = f;
    uint32_t u = v.u;
    uint32_t r = u + 0x7fffu + ((u >> 16) & 1u);
    return (u16)(r >> 16);
}

__global__ __launch_bounds__(256) void convert_both(
    const float* __restrict__ A, const float* __restrict__ B,
    u16* __restrict__ Oa, u16* __restrict__ Ob) {
    const size_t nv8 = (size_t)N_DIM * D_DIM / 8;
    size_t gid = (size_t)blockIdx.x * blockDim.x + threadIdx.x;
    size_t stride = (size_t)gridDim.x * blockDim.x;
    for (size_t i = gid; i < nv8; i += stride) {
        float4 v0 = ((const float4*)A)[2 * i];
        float4 v1 = ((const float4*)A)[2 * i + 1];
        u16x8 o;
        o[0] = f2bf(v0.x); o[1] = f2bf(v0.y); o[2] = f2bf(v0.z); o[3] = f2bf(v0.w);
        o[4] = f2bf(v1.x); o[5] = f2bf(v1.y); o[6] = f2bf(v1.z); o[7] = f2bf(v1.w);
        ((u16x8*)Oa)[i] = o;
    }
    for (size_t i = gid; i < nv8; i += stride) {
        float4 v0 = ((const float4*)B)[2 * i];
        float4 v1 = ((const float4*)B)[2 * i + 1];
        u16x8 o;
        o[0] = f2bf(v0.x); o[1] = f2bf(v0.y); o[2] = f2bf(v0.z); o[3] = f2bf(v0.w);
        o[4] = f2bf(v1.x); o[5] = f2bf(v1.y); o[6] = f2bf(v1.z); o[7] = f2bf(v1.w);
        ((u16x8*)Ob)[i] = o;
    }
}

// ---------- async global->LDS, 16B/lane, wave-uniform LDS base ----------
__device__ __forceinline__ void g2l16(const u16* g, u16* l) {
    __builtin_amdgcn_global_load_lds(
        (const __attribute__((address_space(1))) void*)g,
        (__attribute__((address_space(3))) void*)l,
        16, 0, 0);
}

// ---- Geometry ----
// 256x256 macro-tile, BK=64, 512 threads. A ONLY in LDS: 3 tile-buffers x
// 2 K-half regions (256 rows x 32 bf16 = 16 KB) = 96 KB. B-fragments are
// loaded straight from global into a register double-buffer (bfx/bfy), one
// 32-K slice ahead -- this removes B's 64 KB ds_reads + 32 KB LDS-DMA
// writes per K-tile (the round-0..4 LDS-BW wall: LDS 256 KB/K-tile
// serialized against 2483 cyc of MFMA).
// A swizzle (verified 0 conflicts r0-r4): logical chunk c of row r at
// physical chunk c ^ ((r>>1)&3); inverse applied on the global source.

__device__ __forceinline__ int frag_off(int row, int cbq) {
    return row * 32 + (cbq ^ ((row >> 1) & 3)) * 8;
}

// One phase: 4 A ds_reads (same-phase), 2 B global frag-loads (next slice),
// 1 A-staging g2l, barrier, lgkmcnt(0), 16 MFMA under setprio, vmcnt(9)
// (never 0), barrier. Staging region is consumed >=7 phases after issue;
// vmcnt(9) = 3 phases of 3 loads => everything older than 3 phases is
// complete. B-frag consumption is gated by the compiler's precise
// register-dependency vmcnt waits (loads are compiler-visible).
#define PHASE(ARg, MH, BFU, BFL, JA, JB, BKO, SRCG, LDSD)                     \
  {                                                                           \
    s16x8 af[4];                                                              \
    _Pragma("unroll")                                                         \
    for (int i = 0; i < 4; ++i)                                               \
      af[i] = *(const s16x8*)&(ARg)[(MH) ? aoff1[i] : aoff0[i]];              \
    (BFL)[JA] = *(const s16x8*)(Bbase + brow[JA] + (BKO));                    \
    (BFL)[JB] = *(const s16x8*)(Bbase + brow[JB] + (BKO));                    \
    g2l16((SRCG), (LDSD));                                                    \
    __builtin_amdgcn_s_barrier();                                             \
    asm volatile("s_waitcnt lgkmcnt(0)");                                     \
    __builtin_amdgcn_s_setprio(1);                                            \
    _Pragma("unroll")                                                         \
    for (int i = 0; i < 4; ++i) {                                             \
      _Pragma("unroll")                                                       \
      for (int q = 0; q < 4; ++q)                                             \
        acc[(MH) * 4 + i][q] = __builtin_amdgcn_mfma_f32_16x16x32_bf16(       \
            af[i], (BFU)[q], acc[(MH) * 4 + i][q], 0, 0, 0);                  \
    }                                                                         \
    __builtin_amdgcn_s_setprio(0);                                            \
    asm volatile("s_waitcnt vmcnt(9)");                                       \
    __builtin_amdgcn_s_barrier();                                             \
  }

__global__ __launch_bounds__(512) void gemm_bt_bf16(
    const u16* __restrict__ A, const u16* __restrict__ B, float* __restrict__ C) {
    __shared__ __align__(16) u16 sm[49152];            // 96 KB: 6 A-regions
    u16* R00 = sm;          u16* R01 = sm + 8192;      // buf0 kh0/kh1
    u16* R10 = sm + 16384;  u16* R11 = sm + 24576;     // buf1
    u16* R20 = sm + 32768;  u16* R21 = sm + 40960;     // buf2

    const int tid   = threadIdx.x;
    const int lane  = tid & 63;
    const int wave  = tid >> 6;       // 0..7
    const int waveM = wave >> 2;      // 0..1
    const int waveN = wave & 3;       // 0..3
    const int fr    = lane & 15;
    const int cbq   = lane >> 4;

    // XCD swizzle, 2-col rectangles: each XCD owns 2 B-panels (tileX) x all
    // 16 tileY -> B-gather working set ~2 panels' hot K-slice, L2-resident.
    const int lin  = blockIdx.x;
    const int xcd  = lin & 7;
    const int j    = lin >> 3;                  // 0..31
    const int tileY = j >> 1;                   // 0..15
    const int tileX = xcd * 2 + (j & 1);        // 0..15
    const int rowBase = tileY * 256;
    const int colBase = tileX * 256;

    const u16* Abase = A + (size_t)rowBase * D_DIM;
    const u16* Bbase = B + (size_t)colBase * D_DIM;

    // A staging thread offsets (inverse-swizzled global source), parts 0/1
    size_t srcA[2];
    #pragma unroll
    for (int jj = 0; jj < 2; ++jj) {
        int s = jj * 512 + wave * 64 + lane;    // chunk slot 0..1023
        int r = s >> 2;                         // row 0..255
        int c = (s & 3) ^ ((r >> 1) & 3);
        srcA[jj] = (size_t)r * D_DIM + (size_t)(c * 8);
    }

    // A fragment read offsets (u16 units), MH halves 0/1
    int aoff0[4], aoff1[4];
    #pragma unroll
    for (int i = 0; i < 4; ++i) {
        aoff0[i] = frag_off(waveM * 128 + i * 16 + fr, cbq);
        aoff1[i] = frag_off(waveM * 128 + 64 + i * 16 + fr, cbq);
    }

    // B fragment global row offsets (u16 units): row = waveN*64+j*16+fr,
    // within-row k offset cbq*8; per-frag addr = Bbase + brow[j] + kslice.
    size_t brow[4];
    #pragma unroll
    for (int q = 0; q < 4; ++q)
        brow[q] = (size_t)(waveN * 64 + q * 16 + fr) * D_DIM + (size_t)(cbq * 8);

    f32x4 acc[8][4] = {};
    s16x8 bfx[4], bfy[4];

    // Prologue: stage tiles 0 (buf0) and 1 (buf1) = 8 g2l/thread, then B
    // slice(0,ks0) into bfx. vmcnt(8): tile-0's 4 loads complete; tile-1 and
    // B remain in flight (tile-1 gated by steady-state vmcnt(9); B by the
    // compiler's register-dep wait before the first MFMA).
    g2l16(Abase +  0 + srcA[0], R00 + wave * 512);
    g2l16(Abase +  0 + srcA[1], R00 + 4096 + wave * 512);
    g2l16(Abase + 32 + srcA[0], R01 + wave * 512);
    g2l16(Abase + 32 + srcA[1], R01 + 4096 + wave * 512);
    g2l16(Abase + 64 + srcA[0], R10 + wave * 512);
    g2l16(Abase + 64 + srcA[1], R10 + 4096 + wave * 512);
    g2l16(Abase + 96 + srcA[0], R11 + wave * 512);
    g2l16(Abase + 96 + srcA[1], R11 + 4096 + wave * 512);
    #pragma unroll
    for (int q = 0; q < 4; ++q) bfx[q] = *(const s16x8*)(Bbase + brow[q]);
    asm volatile("s_waitcnt vmcnt(8)");
    __builtin_amdgcn_s_barrier();

    // 64 K-tiles, 3-unrolled (t%3 static: buf = tile%3). Tile tau's 4 phases
    // stage tile tau+2 into buf (tau+2)%3 and prefetch B slices
    // (tau,ks1) then (tau+1,ks0). Clamped tail stages/loads are dead data
    // into soon-unread slots (keep vmcnt counts uniform; addresses in-bounds).
    #pragma unroll 1
    for (int t = 0; t < 63; t += 3) {
        const size_t st0 = (size_t)(t + 2) * 64;
        const size_t st1 = (size_t)((t + 3 < 64) ? t + 3 : 63) * 64;
        const size_t st2 = (size_t)((t + 4 < 64) ? t + 4 : 63) * 64;
        const size_t kc0 = (size_t)t * 64 + 32;
        const size_t kc1 = (size_t)(t + 1) * 64 + 32;
        const size_t kc2 = (size_t)(t + 2) * 64 + 32;
        const size_t kn0 = (size_t)(t + 1) * 64;
        const size_t kn1 = (size_t)(t + 2) * 64;
        const size_t kn2 = (size_t)((t + 3 < 64) ? t + 3 : 63) * 64;

        // tau = t (buf0, stage -> buf2)
        PHASE(R00, 0, bfx, bfy, 0, 1, kc0, Abase + st0      + srcA[0], R20 + wave * 512)
        PHASE(R00, 1, bfx, bfy, 2, 3, kc0, Abase + st0      + srcA[1], R20 + 4096 + wave * 512)
        PHASE(R01, 0, bfy, bfx, 0, 1, kn0, Abase + st0 + 32 + srcA[0], R21 + wave * 512)
        PHASE(R01, 1, bfy, bfx, 2, 3, kn0, Abase + st0 + 32 + srcA[1], R21 + 4096 + wave * 512)
        // tau = t+1 (buf1, stage -> buf0)
        PHASE(R10, 0, bfx, bfy, 0, 1, kc1, Abase + st1      + srcA[0], R00 + wave * 512)
        PHASE(R10, 1, bfx, bfy, 2, 3, kc1, Abase + st1      + srcA[1], R00 + 4096 + wave * 512)
        PHASE(R11, 0, bfy, bfx, 0, 1, kn1, Abase + st1 + 32 + srcA[0], R01 + wave * 512)
        PHASE(R11, 1, bfy, bfx, 2, 3, kn1, Abase + st1 + 32 + srcA[1], R01 + 4096 + wave * 512)
        // tau = t+2 (buf2, stage -> buf1)
        PHASE(R20, 0, bfx, bfy, 0, 1, kc2, Abase + st2      + srcA[0], R10 + wave * 512)
        PHASE(R20, 1, bfx, bfy, 2, 3, kc2, Abase + st2      + srcA[1], R10 + 4096 + wave * 512)
        PHASE(R21, 0, bfy, bfx, 0, 1, kn2, Abase + st2 + 32 + srcA[0], R11 + wave * 512)
        PHASE(R21, 1, bfy, bfx, 2, 3, kn2, Abase + st2 + 32 + srcA[1], R11 + 4096 + wave * 512)
    }
    // Tail: tile 63 (buf0). Stage target buf2 is never read again; B
    // next-slice loads clamped in-bounds (values unused).
    {
        const size_t k63 = (size_t)63 * 64;
        PHASE(R00, 0, bfx, bfy, 0, 1, k63 + 32, Abase + k63      + srcA[0], R20 + wave * 512)
        PHASE(R00, 1, bfx, bfy, 2, 3, k63 + 32, Abase + k63      + srcA[1], R20 + 4096 + wave * 512)
        PHASE(R01, 0, bfy, bfx, 0, 1, k63,      Abase + k63 + 32 + srcA[0], R21 + wave * 512)
        PHASE(R01, 1, bfy, bfx, 2, 3, k63,      Abase + k63 + 32 + srcA[1], R21 + 4096 + wave * 512)
    }

    // Epilogue. C/D layout (verified m89/m91): col = lane&15, row = (lane>>4)*4 + reg
    #pragma unroll
    for (int mt = 0; mt < 8; ++mt) {
        int gr0 = rowBase + waveM * 128 + mt * 16 + (lane >> 4) * 4;
        #pragma unroll
        for (int nt = 0; nt < 4; ++nt) {
            int gc = colBase + waveN * 64 + nt * 16 + (lane & 15);
            #pragma unroll
            for (int r = 0; r < 4; ++r)
                C[(size_t)(gr0 + r) * M_DIM + gc] = acc[mt][nt][r];
        }
    }
}

extern "C" void kernel_launch(void* const* d_in, const int* in_sizes, int n_in,
                              void* d_out, int out_size, void* d_ws, size_t ws_size,
                              hipStream_t stream) {
    const float* A32 = (const float*)d_in[0];
    const float* B32 = (const float*)d_in[1];
    float* C = (float*)d_out;

    u16* Abf = (u16*)d_ws;
    u16* Bbf = Abf + (size_t)N_DIM * D_DIM;

    convert_both<<<4096, 256, 0, stream>>>(A32, B32, Abf, Bbf);
    gemm_bt_bf16<<<256, 512, 0, stream>>>(Abf, Bbf, C);
}

// Round 6
// 284.347 us; speedup vs baseline: 1.2539x; 1.2539x over previous
//
#include <hip/hip_runtime.h>
#include <cstdint>
#include <cstddef>

#define N_DIM 4096
#define M_DIM 4096
#define D_DIM 4096

typedef unsigned short u16;
typedef u16   u16x4 __attribute__((ext_vector_type(4)));
typedef short s16x8 __attribute__((ext_vector_type(8)));   // 8 bf16 (4 VGPRs)
typedef float f32x4 __attribute__((ext_vector_type(4)));   // MFMA accumulator

// ---------- fp32 -> bf16 (RTNE) ----------
__device__ __forceinline__ u16 f2bf(float f) {
    union { float f; uint32_t u; } v; v.f = f;
    uint32_t u = v.u;
    uint32_t r = u + 0x7fffu + ((u >> 16) & 1u);
    return (u16)(r >> 16);
}

// r0-style (float4 load / u16x4 store — the r1 32B-load variant cost ~15 µs),
// fused: A and B converted in the same iteration for 2x memory-level par.
__global__ __launch_bounds__(256) void convert_both(
    const float* __restrict__ A, const float* __restrict__ B,
    u16* __restrict__ Oa, u16* __restrict__ Ob) {
    const size_t nvec = (size_t)N_DIM * D_DIM / 4;
    size_t gid = (size_t)blockIdx.x * blockDim.x + threadIdx.x;
    size_t stride = (size_t)gridDim.x * blockDim.x;
    for (size_t i = gid; i < nvec; i += stride) {
        float4 va = ((const float4*)A)[i];
        float4 vb = ((const float4*)B)[i];
        u16x4 oa, ob;
        oa[0] = f2bf(va.x); oa[1] = f2bf(va.y); oa[2] = f2bf(va.z); oa[3] = f2bf(va.w);
        ob[0] = f2bf(vb.x); ob[1] = f2bf(vb.y); ob[2] = f2bf(vb.z); ob[3] = f2bf(vb.w);
        ((u16x4*)Oa)[i] = oa;
        ((u16x4*)Ob)[i] = ob;
    }
}

// ---------- async global->LDS, 16B/lane, wave-uniform LDS base ----------
__device__ __forceinline__ void g2l16(const u16* g, u16* l) {
    __builtin_amdgcn_global_load_lds(
        (const __attribute__((address_space(1))) void*)g,
        (__attribute__((address_space(3))) void*)l,
        16, 0, 0);
}

// ---- LDS geometry (identical to r2, verified 0 bank conflicts r0-r5) ----
// 8 regions of 16 KB: {A,B} x {buf0,buf1} x {khalf0,khalf1}; region =
// 256 rows x 32 bf16. Row = 64 B = 4 chunks of 16 B; logical chunk c of
// row r stored at physical chunk c ^ ((r>>1)&3); inverse applied on the
// GLOBAL source chunk at staging (LDS dest must stay wave-uniform + lane*16).

__device__ __forceinline__ int frag_off(int row, int cbq) {
    return row * 32 + (cbq ^ ((row >> 1) & 3)) * 8;
}

// MERGED phase = one full K-half for ALL 8 M-frags: 12 ds_read_b128,
// 4 global_load_lds (one A-region + one B-region of a future tile),
// barrier, lgkmcnt(0), 32 MFMA under setprio, vmcnt(8) (never 0), barrier.
// vs r2: same LDS/MFMA totals per K-tile, HALF the barriers/waits/setprio/
// loop overhead (r4 showed read-service already overlaps via wave stagger;
// the residual ~500cyc/phase scales with phase count, so cut phase count).
// vmcnt(8) = 2 phases x 4 loads => loads older than 2 phases complete;
// every region is read 3 phases after staging. WAR: a region is re-staged
// exactly 1 barrier after its last ds_read drains (lgkmcnt(0) precedes that
// phase's end barrier) — same discipline refcheck-passed in r2.
#define PHASE(ARg, BRg, SA, SB, LA, LB)                                       \
  {                                                                           \
    s16x8 af[8], bfr[4];                                                      \
    _Pragma("unroll")                                                         \
    for (int i = 0; i < 8; ++i) af[i]  = *(const s16x8*)&(ARg)[aoff[i]];      \
    _Pragma("unroll")                                                         \
    for (int q = 0; q < 4; ++q) bfr[q] = *(const s16x8*)&(BRg)[boff[q]];      \
    g2l16((SA) + srcA0, (LA) + wave * 512);                                   \
    g2l16((SA) + srcA1, (LA) + 4096 + wave * 512);                            \
    g2l16((SB) + srcA0, (LB) + wave * 512);                                   \
    g2l16((SB) + srcA1, (LB) + 4096 + wave * 512);                            \
    __builtin_amdgcn_s_barrier();                                             \
    asm volatile("s_waitcnt lgkmcnt(0)");                                     \
    __builtin_amdgcn_s_setprio(1);                                            \
    _Pragma("unroll")                                                         \
    for (int i = 0; i < 8; ++i) {                                             \
      _Pragma("unroll")                                                       \
      for (int q = 0; q < 4; ++q)                                             \
        acc[i][q] = __builtin_amdgcn_mfma_f32_16x16x32_bf16(                  \
            af[i], bfr[q], acc[i][q], 0, 0, 0);                               \
    }                                                                         \
    __builtin_amdgcn_s_setprio(0);                                            \
    asm volatile("s_waitcnt vmcnt(8)");                                       \
    __builtin_amdgcn_s_barrier();                                             \
  }

// 256x256 macro-tile, BK=64, 4 merged phases per 2 K-tiles, 512 threads.
__global__ __launch_bounds__(512) void gemm_bt_bf16(
    const u16* __restrict__ A, const u16* __restrict__ B, float* __restrict__ C) {
    __shared__ __align__(16) u16 sm[65536];            // 128 KB
    u16* sA00 = sm;          u16* sA01 = sm + 8192;
    u16* sA10 = sm + 16384;  u16* sA11 = sm + 24576;
    u16* sB00 = sm + 32768;  u16* sB01 = sm + 40960;
    u16* sB10 = sm + 49152;  u16* sB11 = sm + 57344;

    const int tid   = threadIdx.x;
    const int lane  = tid & 63;
    const int wave  = tid >> 6;       // 0..7
    const int waveM = wave >> 2;      // 0..1
    const int waveN = wave & 3;       // 0..3
    const int fr    = lane & 15;
    const int cbq   = lane >> 4;

    // XCD-compact swizzle: 256 blocks, 16x16 tile grid (as r0-r4).
    const int lin  = blockIdx.x;
    const int xcd  = lin & 7;
    const int j    = lin >> 3;
    const int tileY = (xcd >> 1) * 4 + (j & 3);
    const int tileX = (xcd & 1) * 8 + (j >> 2);
    const int rowBase = tileY * 256;
    const int colBase = tileX * 256;

    const u16* Abase = A + (size_t)rowBase * D_DIM;
    const u16* Bbase = B + (size_t)colBase * D_DIM;

    // Thread staging offsets (global source, inverse-swizzled chunk)
    const int s0 = wave * 64 + lane;          // slot 0..511   (region part 0)
    const int s1 = (8 + wave) * 64 + lane;    // slot 512..1023 (part 1)
    const size_t srcA0 = (size_t)(s0 >> 2) * D_DIM + (size_t)(((s0 & 3) ^ ((s0 >> 3) & 3)) * 8);
    const size_t srcA1 = (size_t)(s1 >> 2) * D_DIM + (size_t)(((s1 & 3) ^ ((s1 >> 3) & 3)) * 8);

    // Fragment read offsets (u16 units): 8 M-frags, 4 N-frags
    int aoff[8], boff[4];
    #pragma unroll
    for (int i = 0; i < 8; ++i) aoff[i] = frag_off(waveM * 128 + i * 16 + fr, cbq);
    #pragma unroll
    for (int q = 0; q < 4; ++q) boff[q] = frag_off(waveN * 64 + q * 16 + fr, cbq);

    f32x4 acc[8][4] = {};

    // Prologue: stage t0kh0, t0kh1, t1kh0 (12 loads); vmcnt(8) -> t0kh0
    // landed, 8 outstanding = steady-state phase-entry condition.
    g2l16(Abase + srcA0,      sA00 + wave * 512);
    g2l16(Abase + srcA1,      sA00 + 4096 + wave * 512);
    g2l16(Bbase + srcA0,      sB00 + wave * 512);
    g2l16(Bbase + srcA1,      sB00 + 4096 + wave * 512);
    g2l16(Abase + 32 + srcA0, sA01 + wave * 512);
    g2l16(Abase + 32 + srcA1, sA01 + 4096 + wave * 512);
    g2l16(Bbase + 32 + srcA0, sB01 + wave * 512);
    g2l16(Bbase + 32 + srcA1, sB01 + 4096 + wave * 512);
    g2l16(Abase + 64 + srcA0, sA10 + wave * 512);
    g2l16(Abase + 64 + srcA1, sA10 + 4096 + wave * 512);
    g2l16(Bbase + 64 + srcA0, sB10 + wave * 512);
    g2l16(Bbase + 64 + srcA1, sB10 + 4096 + wave * 512);
    asm volatile("s_waitcnt vmcnt(8)");
    __builtin_amdgcn_s_barrier();

    // Phase p stages a region-pair read at phase p+3 (>=2 needed for vmcnt(8)).
    // Tail clamps re-stage tile 63 into buffers never read again (dead data,
    // keeps per-phase load counts uniform, addresses in-bounds).
    #pragma unroll 1
    for (int t = 0; t < 64; t += 2) {
        const int t2 = (t + 2 < 64) ? t + 2 : 63;
        const int t3 = (t + 3 < 64) ? t + 3 : 63;
        const u16* A1h = Abase + (t + 1) * 64 + 32;   // (t+1) kh1
        const u16* B1h = Bbase + (t + 1) * 64 + 32;
        const u16* A20 = Abase + t2 * 64;             // (t+2) kh0
        const u16* B20 = Bbase + t2 * 64;
        const u16* A21 = Abase + t2 * 64 + 32;        // (t+2) kh1
        const u16* B21 = Bbase + t2 * 64 + 32;
        const u16* A30 = Abase + t3 * 64;             // (t+3) kh0
        const u16* B30 = Bbase + t3 * 64;

        PHASE(sA00, sB00, A1h, B1h, sA11, sB11)   // tile t   kh0
        PHASE(sA01, sB01, A20, B20, sA00, sB00)   // tile t   kh1
        PHASE(sA10, sB10, A21, B21, sA01, sB01)   // tile t+1 kh0
        PHASE(sA11, sB11, A30, B30, sA10, sB10)   // tile t+1 kh1
    }

    // Epilogue. C/D layout (verified m89/m91): col = lane&15, row = (lane>>4)*4 + reg
    #pragma unroll
    for (int mt = 0; mt < 8; ++mt) {
        int gr0 = rowBase + waveM * 128 + mt * 16 + (lane >> 4) * 4;
        #pragma unroll
        for (int nt = 0; nt < 4; ++nt) {
            int gc = colBase + waveN * 64 + nt * 16 + (lane & 15);
            #pragma unroll
            for (int r = 0; r < 4; ++r)
                C[(size_t)(gr0 + r) * M_DIM + gc] = acc[mt][nt][r];
        }
    }
}

extern "C" void kernel_launch(void* const* d_in, const int* in_sizes, int n_in,
                              void* d_out, int out_size, void* d_ws, size_t ws_size,
                              hipStream_t stream) {
    const float* A32 = (const float*)d_in[0];
    const float* B32 = (const float*)d_in[1];
    float* C = (float*)d_out;

    u16* Abf = (u16*)d_ws;
    u16* Bbf = Abf + (size_t)N_DIM * D_DIM;

    convert_both<<<4096, 256, 0, stream>>>(A32, B32, Abf, Bbf);
    gemm_bt_bf16<<<256, 512, 0, stream>>>(Abf, Bbf, C);
}

// Round 7
// 281.798 us; speedup vs baseline: 1.2653x; 1.0090x over previous
//
#include <hip/hip_runtime.h>
#include <cstdint>
#include <cstddef>

#define N_DIM 4096
#define M_DIM 4096
#define D_DIM 4096

typedef unsigned short u16;
typedef u16   u16x4 __attribute__((ext_vector_type(4)));
typedef short s16x8 __attribute__((ext_vector_type(8)));   // 8 bf16 (4 VGPRs)
typedef float f32x4 __attribute__((ext_vector_type(4)));   // MFMA accumulator

// ---------- fp32 -> bf16 (RTNE) ----------
__device__ __forceinline__ u16 f2bf(float f) {
    union { float f; uint32_t u; } v; v.f = f;
    uint32_t u = v.u;
    uint32_t r = u + 0x7fffu + ((u >> 16) & 1u);
    return (u16)(r >> 16);
}

// EXACT r0 convert (separate loops, float4 loads, u16x4 stores): residual
// ledger shows this form at 143.8 µs vs 153-160 for every variant since.
__global__ __launch_bounds__(256) void convert_both(
    const float* __restrict__ A, const float* __restrict__ B,
    u16* __restrict__ Oa, u16* __restrict__ Ob) {
    const size_t nvec = (size_t)N_DIM * D_DIM / 4;
    size_t gid = (size_t)blockIdx.x * blockDim.x + threadIdx.x;
    size_t stride = (size_t)gridDim.x * blockDim.x;
    for (size_t i = gid; i < nvec; i += stride) {
        float4 v = ((const float4*)A)[i];
        u16x4 o; o[0] = f2bf(v.x); o[1] = f2bf(v.y); o[2] = f2bf(v.z); o[3] = f2bf(v.w);
        ((u16x4*)Oa)[i] = o;
    }
    for (size_t i = gid; i < nvec; i += stride) {
        float4 v = ((const float4*)B)[i];
        u16x4 o; o[0] = f2bf(v.x); o[1] = f2bf(v.y); o[2] = f2bf(v.z); o[3] = f2bf(v.w);
        ((u16x4*)Ob)[i] = o;
    }
}

// ---------- async global->LDS, 16B/lane, wave-uniform LDS base ----------
__device__ __forceinline__ void g2l16(const u16* g, u16* l) {
    __builtin_amdgcn_global_load_lds(
        (const __attribute__((address_space(1))) void*)g,
        (__attribute__((address_space(3))) void*)l,
        16, 0, 0);
}

// ---- LDS geometry (identical to r2, verified 0 bank conflicts r0-r6) ----
// 8 regions of 16 KB: {A,B} x {buf0,buf1} x {khalf0,khalf1}; region =
// 256 rows x 32 bf16. Row = 64 B = 4 chunks of 16 B; logical chunk c of
// row r stored at physical chunk c ^ ((r>>1)&3); inverse applied on the
// GLOBAL source chunk at staging (LDS dest must stay wave-uniform + lane*16).

__device__ __forceinline__ int frag_off(int row, int cbq) {
    return row * 32 + (cbq ^ ((row >> 1) & 3)) * 8;
}

// Stage one full region (2 loads/thread)
#define STG(G, L)                                                             \
    g2l16((G) + srcA0, (L) + wave * 512);                                     \
    g2l16((G) + srcA1, (L) + 4096 + wave * 512);

// Phase: 4 A ds_reads (+4 B on MH==0), stage stmts, barrier, lgkmcnt(0),
// 16 MFMA under setprio, [vmcnt(4) on DOVM phases only], barrier.
// vs r2: counted vmcnt at 2 of 8 phases (was 4 of 8) and stage->read
// distance 6-7 phases (was 3) — the m201 "counted vmcnt once per K-tile,
// never 0" discipline. Ledger (stage slot -> covering wait -> first read):
//   P0: sA11,sB11 <- (t+1)k1 | end-P3 vmcnt(4)           | read P6,P7
//   P2: sA00      <- (t+2)k0 | end-P7 vmcnt(4)           | read P0',P1'
//   P3: sB00      <- (t+2)k0 | end-P7 vmcnt(4)           | read P0',P1'
//   P4: sA01,sB01 <- (t+2)k1 | end-P7 vmcnt(4)           | read P2',P3'
//   P6: sA10      <- (t+3)k0 | next end-P3 vmcnt(4)      | read P4',P5'
//   P7: sB10      <- (t+3)k0 | next end-P3 vmcnt(4)      | read P4',P5'
// end-P3 outstanding = {prevP6(2),prevP7(2),P0(4),P2(2),P3(2)}=12, keep 4
//   => drains prevP6,prevP7,P0 ✓.  end-P7 outstanding = {P4(4),P6(2),
//   P7(2)}=8, keep 4 => drains P4 (and older) ✓.
// WAR: every re-stage at phase p overwrites a region last ds-read at
// phase <= p-1, drained by that phase's lgkmcnt(0) before its end
// barrier, which all waves pass before any phase-p stage issue ✓.
#define PHASE(AR, BR, MH, DOVM, ...)                                          \
  {                                                                           \
    s16x8 af[4];                                                              \
    _Pragma("unroll")                                                         \
    for (int i = 0; i < 4; ++i)                                               \
      af[i] = *(const s16x8*)&(AR)[(MH) ? aoff1[i] : aoff0[i]];               \
    if (!(MH)) {                                                              \
      _Pragma("unroll")                                                       \
      for (int q = 0; q < 4; ++q)                                             \
        bfp[q] = *(const s16x8*)&(BR)[boff[q]];                               \
    }                                                                         \
    __VA_ARGS__                                                               \
    __builtin_amdgcn_s_barrier();                                             \
    asm volatile("s_waitcnt lgkmcnt(0)");                                     \
    __builtin_amdgcn_s_setprio(1);                                            \
    _Pragma("unroll")                                                         \
    for (int i = 0; i < 4; ++i) {                                             \
      _Pragma("unroll")                                                       \
      for (int q = 0; q < 4; ++q)                                             \
        acc[(MH) * 4 + i][q] = __builtin_amdgcn_mfma_f32_16x16x32_bf16(       \
            af[i], bfp[q], acc[(MH) * 4 + i][q], 0, 0, 0);                    \
    }                                                                         \
    __builtin_amdgcn_s_setprio(0);                                            \
    if (DOVM) asm volatile("s_waitcnt vmcnt(4)");                             \
    __builtin_amdgcn_s_barrier();                                             \
  }

// 256x256 macro-tile, BK=64, 8 phases / 2 K-tiles, 512 threads.
__global__ __launch_bounds__(512) void gemm_bt_bf16(
    const u16* __restrict__ A, const u16* __restrict__ B, float* __restrict__ C) {
    __shared__ __align__(16) u16 sm[65536];            // 128 KB
    u16* sA00 = sm;          u16* sA01 = sm + 8192;
    u16* sA10 = sm + 16384;  u16* sA11 = sm + 24576;
    u16* sB00 = sm + 32768;  u16* sB01 = sm + 40960;
    u16* sB10 = sm + 49152;  u16* sB11 = sm + 57344;

    const int tid   = threadIdx.x;
    const int lane  = tid & 63;
    const int wave  = tid >> 6;       // 0..7
    const int waveM = wave >> 2;      // 0..1
    const int waveN = wave & 3;       // 0..3
    const int fr    = lane & 15;
    const int cbq   = lane >> 4;

    // XCD-compact swizzle: 256 blocks, 16x16 tile grid (as r0-r6).
    const int lin  = blockIdx.x;
    const int xcd  = lin & 7;
    const int j    = lin >> 3;
    const int tileY = (xcd >> 1) * 4 + (j & 3);
    const int tileX = (xcd & 1) * 8 + (j >> 2);
    const int rowBase = tileY * 256;
    const int colBase = tileX * 256;

    const u16* Abase = A + (size_t)rowBase * D_DIM;
    const u16* Bbase = B + (size_t)colBase * D_DIM;

    // Thread staging offsets (global source, inverse-swizzled chunk)
    const int s0 = wave * 64 + lane;          // slot 0..511   (region part 0)
    const int s1 = (8 + wave) * 64 + lane;    // slot 512..1023 (part 1)
    const size_t srcA0 = (size_t)(s0 >> 2) * D_DIM + (size_t)(((s0 & 3) ^ ((s0 >> 3) & 3)) * 8);
    const size_t srcA1 = (size_t)(s1 >> 2) * D_DIM + (size_t)(((s1 & 3) ^ ((s1 >> 3) & 3)) * 8);

    // Fragment read offsets (u16 units)
    int aoff0[4], aoff1[4], boff[4];
    #pragma unroll
    for (int i = 0; i < 4; ++i) {
        aoff0[i] = frag_off(waveM * 128 + i * 16 + fr, cbq);
        aoff1[i] = frag_off(waveM * 128 + 64 + i * 16 + fr, cbq);
        boff[i]  = frag_off(waveN * 64 + i * 16 + fr, cbq);
    }

    f32x4 acc[8][4] = {};
    s16x8 bfp[4];

    // Prologue: stage t0(k0,k1) + t1(k0) = 12 loads; vmcnt(4) drains t0's 8
    // (needed at P0/P2), leaves t1k0's 4 in flight (drained by end-P3 wait,
    // needed at P4) — matches the steady-state ledger above.
    STG(Abase,      sA00)  STG(Bbase,      sB00)
    STG(Abase + 32, sA01)  STG(Bbase + 32, sB01)
    STG(Abase + 64, sA10)  STG(Bbase + 64, sB10)
    asm volatile("s_waitcnt vmcnt(4)");
    __builtin_amdgcn_s_barrier();

    // Tail clamps stage tile-63 data into regions never read again (dead,
    // keeps per-phase load counts uniform, addresses in-bounds). P0's
    // (t+1)k1 stage is always live data (t+1 <= 63).
    #pragma unroll 1
    for (int t = 0; t < 64; t += 2) {
        const int t2 = (t + 2 < 64) ? t + 2 : 63;
        const int t3 = (t + 3 < 64) ? t + 3 : 63;
        const u16* A1k1 = Abase + (t + 1) * 64 + 32;
        const u16* B1k1 = Bbase + (t + 1) * 64 + 32;
        const u16* A2k0 = Abase + t2 * 64;
        const u16* B2k0 = Bbase + t2 * 64;
        const u16* A2k1 = Abase + t2 * 64 + 32;
        const u16* B2k1 = Bbase + t2 * 64 + 32;
        const u16* A3k0 = Abase + t3 * 64;
        const u16* B3k0 = Bbase + t3 * 64;

        PHASE(sA00, sB00, 0, 0, STG(A1k1, sA11) STG(B1k1, sB11))  // P0
        PHASE(sA00, sB00, 1, 0, )                                 // P1
        PHASE(sA01, sB01, 0, 0, STG(A2k0, sA00))                  // P2
        PHASE(sA01, sB01, 1, 1, STG(B2k0, sB00))                  // P3 vmcnt
        PHASE(sA10, sB10, 0, 0, STG(A2k1, sA01) STG(B2k1, sB01))  // P4
        PHASE(sA10, sB10, 1, 0, )                                 // P5
        PHASE(sA11, sB11, 0, 0, STG(A3k0, sA10))                  // P6
        PHASE(sA11, sB11, 1, 1, STG(B3k0, sB10))                  // P7 vmcnt
    }

    // Epilogue. C/D layout (verified m89/m91): col = lane&15, row = (lane>>4)*4 + reg
    #pragma unroll
    for (int mt = 0; mt < 8; ++mt) {
        int gr0 = rowBase + waveM * 128 + mt * 16 + (lane >> 4) * 4;
        #pragma unroll
        for (int nt = 0; nt < 4; ++nt) {
            int gc = colBase + waveN * 64 + nt * 16 + (lane & 15);
            #pragma unroll
            for (int r = 0; r < 4; ++r)
                C[(size_t)(gr0 + r) * M_DIM + gc] = acc[mt][nt][r];
        }
    }
}

extern "C" void kernel_launch(void* const* d_in, const int* in_sizes, int n_in,
                              void* d_out, int out_size, void* d_ws, size_t ws_size,
                              hipStream_t stream) {
    const float* A32 = (const float*)d_in[0];
    const float* B32 = (const float*)d_in[1];
    float* C = (float*)d_out;

    u16* Abf = (u16*)d_ws;
    u16* Bbf = Abf + (size_t)N_DIM * D_DIM;

    convert_both<<<4096, 256, 0, stream>>>(A32, B32, Abf, Bbf);
    gemm_bt_bf16<<<256, 512, 0, stream>>>(Abf, Bbf, C);
}